// Round 13
// baseline (1652.375 us; speedup 1.0000x reference)
//
#include <hip/hip_runtime.h>
#include <cmath>

#define D_MODEL 1024
#define N_HEADS 16
#define DKH     64
#define SEQ_T   1024
#define BATCH   2
#define VOCAB   32000
#define DFF_    4096
#define NLAYERS 8

typedef __bf16 bf16x8 __attribute__((ext_vector_type(8)));
typedef __bf16 bf16x4v __attribute__((ext_vector_type(4)));
typedef float  f32x4  __attribute__((ext_vector_type(4)));

__device__ __forceinline__ float gelu_f(float x) {
    return 0.5f * x * (1.0f + erff(x * 0.70710678118654752f));
}

__device__ __forceinline__ void gload_lds16(const void* g, void* l) {
    __builtin_amdgcn_global_load_lds(
        (const __attribute__((address_space(1))) void*)g,
        (__attribute__((address_space(3))) void*)l, 16, 0, 0);
}

// ---------------------------------------------------------------------------
// Embedding: h (bf16) = inp_emb[x] + pos_emb. 4 elems/thread.
// ---------------------------------------------------------------------------
__global__ __launch_bounds__(256) void embed_kernel(
    const int* __restrict__ x, const float* __restrict__ inp_emb,
    const float* __restrict__ pos_emb, __bf16* __restrict__ h)
{
    const int idx = (blockIdx.x * 256 + threadIdx.x) * 4;
    const int bt  = idx >> 10;
    const int d   = idx & 1023;
    const int t   = bt & (SEQ_T - 1);
    const int tok = x[bt];
    const float4 a = *(const float4*)(inp_emb + (size_t)tok * D_MODEL + d);
    const float4 b = *(const float4*)(pos_emb + (size_t)t * D_MODEL + d);
    bf16x4v o;
    o[0] = (__bf16)(a.x + b.x);
    o[1] = (__bf16)(a.y + b.y);
    o[2] = (__bf16)(a.z + b.z);
    o[3] = (__bf16)(a.w + b.w);
    *(bf16x4v*)(h + idx) = o;
}

// ---------------------------------------------------------------------------
// LayerNorm body (D=1024), bf16 in, bf16 out. One 256-thr block per row.
// ---------------------------------------------------------------------------
__device__ __forceinline__ void ln_row(
    const __bf16* __restrict__ x, const float* __restrict__ sc,
    const float* __restrict__ bi, __bf16* __restrict__ o, int row, int tid)
{
    const int c = tid * 4;
    const bf16x4v v4 = *(const bf16x4v*)(x + (size_t)row * D_MODEL + c);
    const float vx = (float)v4[0], vy = (float)v4[1], vz = (float)v4[2], vw = (float)v4[3];
    float sum = vx + vy + vz + vw;
    float sq  = vx * vx + vy * vy + vz * vz + vw * vw;
    #pragma unroll
    for (int off = 32; off > 0; off >>= 1) {
        sum += __shfl_xor(sum, off);
        sq  += __shfl_xor(sq, off);
    }
    __shared__ float ssum[4], ssq[4];
    const int wave = tid >> 6, lane = tid & 63;
    if (lane == 0) { ssum[wave] = sum; ssq[wave] = sq; }
    __syncthreads();
    sum = ssum[0] + ssum[1] + ssum[2] + ssum[3];
    sq  = ssq[0]  + ssq[1]  + ssq[2]  + ssq[3];
    const float mu  = sum * (1.0f / D_MODEL);
    const float var = sq * (1.0f / D_MODEL) - mu * mu;
    const float rs  = rsqrtf(var + 1e-5f);
    const float4 s4 = *(const float4*)(sc + c);
    const float4 b4 = *(const float4*)(bi + c);
    bf16x4v ov;
    ov[0] = (__bf16)((vx - mu) * rs * s4.x + b4.x);
    ov[1] = (__bf16)((vy - mu) * rs * s4.y + b4.y);
    ov[2] = (__bf16)((vz - mu) * rs * s4.z + b4.z);
    ov[3] = (__bf16)((vw - mu) * rs * s4.w + b4.w);
    *(bf16x4v*)(o + (size_t)row * D_MODEL + c) = ov;
}

__global__ __launch_bounds__(256) void layernorm_kernel(
    const __bf16* __restrict__ x, const float* __restrict__ sc,
    const float* __restrict__ bi, __bf16* __restrict__ o)
{
    ln_row(x, sc, bi, o, blockIdx.x, threadIdx.x);
}

// ---------------------------------------------------------------------------
// w_out transpose (blocks 0..15999) + final LN (blocks 16000..18047).
// Placed right before the logits GEMM so woutT is L3-resident (r12 lesson).
// ---------------------------------------------------------------------------
__global__ __launch_bounds__(256) void wout_ln_kernel(
    const float* __restrict__ in, __bf16* __restrict__ out,
    const __bf16* __restrict__ h, const float* __restrict__ lno_s,
    const float* __restrict__ lno_b, __bf16* __restrict__ xn)
{
    const int tid = threadIdx.x;
    if (blockIdx.x >= 16000) {
        ln_row(h, lno_s, lno_b, xn, blockIdx.x - 16000, tid);
        return;
    }
    __shared__ __bf16 tile[32][72];
    const int t   = blockIdx.x;
    const int kb0 = (t & 31) * 32;
    const int nb0 = (t >> 5) * 64;
    {
        const int rr = tid >> 3, c8 = (tid & 7) * 8;
        const float* p = in + (size_t)(kb0 + rr) * VOCAB + nb0 + c8;
        const float4 v0 = *(const float4*)p;
        const float4 v1 = *(const float4*)(p + 4);
        tile[rr][c8 + 0] = (__bf16)v0.x;
        tile[rr][c8 + 1] = (__bf16)v0.y;
        tile[rr][c8 + 2] = (__bf16)v0.z;
        tile[rr][c8 + 3] = (__bf16)v0.w;
        tile[rr][c8 + 4] = (__bf16)v1.x;
        tile[rr][c8 + 5] = (__bf16)v1.y;
        tile[rr][c8 + 6] = (__bf16)v1.z;
        tile[rr][c8 + 7] = (__bf16)v1.w;
    }
    __syncthreads();
    {
        const int cc = tid >> 2, k8 = (tid & 3) * 8;
        bf16x8 ov;
        #pragma unroll
        for (int e = 0; e < 8; ++e) ov[e] = tile[k8 + e][cc];
        *(bf16x8*)(out + (size_t)(nb0 + cc) * D_MODEL + kb0 + k8) = ov;
    }
}

// ---------------------------------------------------------------------------
// Merged per-layer dispatch: LN1 (blocks 0..2047) + 6 weight transposes
// (f32 [K][N] -> bf16 [N][K], 32x64 tiles, bf16x8 writes) + qkv bias concat.
// ---------------------------------------------------------------------------
__global__ __launch_bounds__(256) void prep_ln_kernel(
    const __bf16* __restrict__ h, const float* __restrict__ ln_s,
    const float* __restrict__ ln_b, __bf16* __restrict__ xn,
    const float* __restrict__ wq, const float* __restrict__ wk,
    const float* __restrict__ wv, const float* __restrict__ wo,
    const float* __restrict__ w1, const float* __restrict__ w2,
    const float* __restrict__ bq, const float* __restrict__ bk,
    const float* __restrict__ bv,
    __bf16* __restrict__ wqkvT, __bf16* __restrict__ woT,
    __bf16* __restrict__ w1T, __bf16* __restrict__ w2T,
    float* __restrict__ bqkv)
{
    const int tid = threadIdx.x;
    const int b   = blockIdx.x;

    if (b < 2048) {                       // LN1
        ln_row(h, ln_s, ln_b, xn, b, tid);
        return;
    }
    const int pb = b - 2048;
    if (pb >= 6144) {                     // bias concat (12 blocks)
        const int j = (pb - 6144) * 256 + tid;
        bqkv[j] = (j < 1024) ? bq[j] : (j < 2048 ? bk[j - 1024] : bv[j - 2048]);
        return;
    }

    // 32(K) x 64(N) transpose tile
    __shared__ __bf16 tile[32][72];
    const float* in;
    __bf16* out;
    int K, N, kb0, nb0;
    if (pb < 2048) {                      // wq/wk/wv/wo: 512 tiles each
        const int w = pb >> 9, t = pb & 511;
        K = 1024; N = 1024; kb0 = (t >> 4) * 32; nb0 = (t & 15) * 64;
        in  = (w == 0) ? wq : (w == 1) ? wk : (w == 2) ? wv : wo;
        out = (w == 3) ? woT : wqkvT + (size_t)w * 1024 * 1024;
    } else if (pb < 4096) {               // w1: K=1024, N=4096
        const int t = pb - 2048;
        K = 1024; N = 4096; kb0 = (t >> 6) * 32; nb0 = (t & 63) * 64;
        in = w1; out = w1T;
    } else {                              // w2: K=4096, N=1024
        const int t = pb - 4096;
        K = 4096; N = 1024; kb0 = (t >> 4) * 32; nb0 = (t & 15) * 64;
        in = w2; out = w2T;
    }

    {   // read: 32 rows x 64 cols, 8 f32 per thread
        const int rr = tid >> 3, c8 = (tid & 7) * 8;
        const float* p = in + (size_t)(kb0 + rr) * N + nb0 + c8;
        const float4 v0 = *(const float4*)p;
        const float4 v1 = *(const float4*)(p + 4);
        tile[rr][c8 + 0] = (__bf16)v0.x;
        tile[rr][c8 + 1] = (__bf16)v0.y;
        tile[rr][c8 + 2] = (__bf16)v0.z;
        tile[rr][c8 + 3] = (__bf16)v0.w;
        tile[rr][c8 + 4] = (__bf16)v1.x;
        tile[rr][c8 + 5] = (__bf16)v1.y;
        tile[rr][c8 + 6] = (__bf16)v1.z;
        tile[rr][c8 + 7] = (__bf16)v1.w;
    }
    __syncthreads();
    {   // write: 64 cols x 32 k, bf16x8 (16B) per thread
        const int cc = tid >> 2, k8 = (tid & 3) * 8;
        bf16x8 ov;
        #pragma unroll
        for (int e = 0; e < 8; ++e) ov[e] = tile[k8 + e][cc];
        *(bf16x8*)(out + (size_t)(nb0 + cc) * K + kb0 + k8) = ov;
    }
}

// ---------------------------------------------------------------------------
// GEMM: C[M,N] = epi(A[M,K] @ Bt[N,K]^T + bias). bf16 in, f32 acc.
// Single-buffered m97 structure: 128 x BN_T tile, BK=64, global_load_lds
// staging, XOR-granule swizzle both sides, M-fast grid + XCD chunking.
// EPI: 0 bias; 1 bias+residual (res type = OutT); 2 bias+GELU.
// NT: direct nontemporal C stores (streaming output).
// ---------------------------------------------------------------------------
template <int BN_T, int EPI, typename OutT, bool NT = false>
__global__ __launch_bounds__(256) void gemm_bt(
    const __bf16* __restrict__ A, const __bf16* __restrict__ Bt,
    const float* __restrict__ bias, const OutT* __restrict__ res,
    OutT* __restrict__ C, int M, int N, int K)
{
    constexpr int NF  = BN_T / 32;
    constexpr int NCB = BN_T / 8;
    __shared__ __bf16 As[128 * 64];
    __shared__ __bf16 Bs[BN_T * 64];

    const int tid  = threadIdx.x;
    const int wave = tid >> 6;
    const int lane = tid & 63;
    const int r    = lane & 15;
    const int kb   = lane >> 4;
    const int wm   = wave >> 1;
    const int wn   = wave & 1;

    const int ntm = gridDim.x;
    const int nwg = ntm * gridDim.y;
    int bid = blockIdx.y * ntm + blockIdx.x;
    if ((nwg & 7) == 0) bid = (bid & 7) * (nwg >> 3) + (bid >> 3);
    const int bm = (bid % ntm) * 128;
    const int bn = (bid / ntm) * BN_T;

    const int srow = lane >> 3;
    const int sg   = lane & 7;

    f32x4 acc[4][NF] = {};

    for (int k0 = 0; k0 < K; k0 += 64) {
        #pragma unroll
        for (int i = 0; i < 4; ++i) {
            const int c    = i * 4 + wave;
            const int row  = c * 8 + srow;
            const int scol = (sg ^ (row & 7)) * 8;
            gload_lds16(A + (size_t)(bm + row) * K + k0 + scol, &As[c * 512]);
        }
        #pragma unroll
        for (int i = 0; i < NCB / 4; ++i) {
            const int c    = i * 4 + wave;
            const int row  = c * 8 + srow;
            const int scol = (sg ^ (row & 7)) * 8;
            gload_lds16(Bt + (size_t)(bn + row) * K + k0 + scol, &Bs[c * 512]);
        }
        __syncthreads();

        #pragma unroll
        for (int s = 0; s < 2; ++s) {
            bf16x8 af[4];
            #pragma unroll
            for (int m = 0; m < 4; ++m) {
                const int row = wm * 64 + m * 16 + r;
                const int g   = (s * 4 + kb) ^ (row & 7);
                af[m] = *(const bf16x8*)&As[row * 64 + g * 8];
            }
            #pragma unroll
            for (int n = 0; n < NF; ++n) {
                const int row = wn * (NF * 16) + n * 16 + r;
                const int g   = (s * 4 + kb) ^ (row & 7);
                const bf16x8 bfr = *(const bf16x8*)&Bs[row * 64 + g * 8];
                #pragma unroll
                for (int m = 0; m < 4; ++m)
                    acc[m][n] = __builtin_amdgcn_mfma_f32_16x16x32_bf16(af[m], bfr, acc[m][n], 0, 0, 0);
            }
        }
        __syncthreads();
    }

    #pragma unroll
    for (int m = 0; m < 4; ++m) {
        const int row = bm + wm * 64 + m * 16 + kb * 4;
        #pragma unroll
        for (int n = 0; n < NF; ++n) {
            const int col = bn + wn * (NF * 16) + n * 16 + r;
            const float bv = bias ? bias[col] : 0.0f;
            #pragma unroll
            for (int rg = 0; rg < 4; ++rg) {
                float v = acc[m][n][rg] + bv;
                if constexpr (EPI == 1) v += (float)res[(size_t)(row + rg) * N + col];
                if constexpr (EPI == 2) v = gelu_f(v);
                if constexpr (NT) {
                    __builtin_nontemporal_store((OutT)v, &C[(size_t)(row + rg) * N + col]);
                } else {
                    C[(size_t)(row + rg) * N + col] = (OutT)v;
                }
            }
        }
    }
}

// ---------------------------------------------------------------------------
// Balanced MFMA flash attention (causal), bf16 packed qkv (row stride 3072).
// One block = (b, h, query-tile PAIR {i, 15-i}), 4 waves x 16 q per tile.
// Diagonal-only masking + defer-max (THR=8) + T14 async-STAGE split
// + K/V LDS DOUBLE-BUFFER: ONE barrier per KV-tile (write buf^1 after
// computing buf; end-of-iter barrier separates it from last iter's reads).
// ---------------------------------------------------------------------------
struct AttnState {
    float m[4];
    float l[4];
    f32x4 yacc[4];
};

template <bool MASK>
__device__ __forceinline__ void attn_tile_step(
    AttnState& st, const bf16x8 (&qf)[2], int q0, int kt,
    int wave, int r, int kb,
    const __bf16 (*K_lds)[72], const __bf16 (*V_lds)[72],
    __bf16 (*P_row)[72])
{
    f32x4 sacc[4] = {};
    #pragma unroll
    for (int kc = 0; kc < 2; ++kc) {
        #pragma unroll
        for (int g = 0; g < 4; ++g) {
            const bf16x8 kf = *(const bf16x8*)&K_lds[g * 16 + r][kc * 32 + kb * 8];
            sacc[g] = __builtin_amdgcn_mfma_f32_16x16x32_bf16(qf[kc], kf, sacc[g], 0, 0, 0);
        }
    }

    float s[4][4], p[4][4];
    #pragma unroll
    for (int g = 0; g < 4; ++g) {
        #pragma unroll
        for (int rg = 0; rg < 4; ++rg) {
            if constexpr (MASK) {
                const int key = kt * 64 + g * 16 + r;
                const int qq  = q0 + wave * 16 + kb * 4 + rg;
                s[g][rg] = (key <= qq) ? sacc[g][rg] * 0.125f : -INFINITY;
            } else {
                s[g][rg] = sacc[g][rg] * 0.125f;
            }
        }
    }

    float mt[4];
    #pragma unroll
    for (int rg = 0; rg < 4; ++rg)
        mt[rg] = fmaxf(fmaxf(s[0][rg], s[1][rg]), fmaxf(s[2][rg], s[3][rg]));
    #pragma unroll
    for (int off = 1; off < 16; off <<= 1) {
        #pragma unroll
        for (int rg = 0; rg < 4; ++rg) mt[rg] = fmaxf(mt[rg], __shfl_xor(mt[rg], off));
    }

    bool grow = false;
    #pragma unroll
    for (int rg = 0; rg < 4; ++rg) grow |= (mt[rg] > st.m[rg] + 8.0f);
    if (__any(grow)) {
        #pragma unroll
        for (int rg = 0; rg < 4; ++rg) {
            const float mn   = fmaxf(st.m[rg], mt[rg]);
            const float corr = __expf(st.m[rg] - mn);
            st.l[rg] *= corr;
            st.m[rg]  = mn;
            #pragma unroll
            for (int n = 0; n < 4; ++n) st.yacc[n][rg] *= corr;
        }
    }

    float psum[4];
    #pragma unroll
    for (int rg = 0; rg < 4; ++rg) {
        psum[rg] = 0.0f;
        #pragma unroll
        for (int g = 0; g < 4; ++g) {
            p[g][rg] = __expf(s[g][rg] - st.m[rg]);
            psum[rg] += p[g][rg];
        }
    }
    #pragma unroll
    for (int off = 1; off < 16; off <<= 1) {
        #pragma unroll
        for (int rg = 0; rg < 4; ++rg) psum[rg] += __shfl_xor(psum[rg], off);
    }
    #pragma unroll
    for (int rg = 0; rg < 4; ++rg) st.l[rg] += psum[rg];

    #pragma unroll
    for (int g = 0; g < 4; ++g) {
        #pragma unroll
        for (int rg = 0; rg < 4; ++rg)
            P_row[kb * 4 + rg][g * 16 + r] = (__bf16)p[g][rg];
    }
    const bf16x8 pa0 = *(const bf16x8*)&P_row[r][kb * 8];
    const bf16x8 pa1 = *(const bf16x8*)&P_row[r][32 + kb * 8];

    #pragma unroll
    for (int n = 0; n < 4; ++n) {
        const int vrow = n * 16 + r;
        const int swz  = (vrow >> 3) & 7;
        const bf16x8 vf0 = *(const bf16x8*)&V_lds[vrow][(kb ^ swz) * 8];
        st.yacc[n] = __builtin_amdgcn_mfma_f32_16x16x32_bf16(pa0, vf0, st.yacc[n], 0, 0, 0);
    }
    #pragma unroll
    for (int n = 0; n < 4; ++n) {
        const int vrow = n * 16 + r;
        const int swz  = (vrow >> 3) & 7;
        const bf16x8 vf1 = *(const bf16x8*)&V_lds[vrow][((kb + 4) ^ swz) * 8];
        st.yacc[n] = __builtin_amdgcn_mfma_f32_16x16x32_bf16(pa1, vf1, st.yacc[n], 0, 0, 0);
    }
}

__global__ __launch_bounds__(256) void attn_mfma_kernel(
    const __bf16* __restrict__ qkv, __bf16* __restrict__ y)
{
    constexpr int QS = 3 * D_MODEL;
    __shared__ __align__(16) __bf16 K_lds[2][64][72];
    __shared__ __align__(16) __bf16 V_lds[2][64][72];
    __shared__ __align__(16) __bf16 P_lds[4][16][72];

    const int tid  = threadIdx.x;
    const int wave = tid >> 6;
    const int lane = tid & 63;
    const int r    = lane & 15;
    const int kb   = lane >> 4;

    const int ip  = blockIdx.x;           // 0..7
    const int q0A = ip * 64;
    const int q0B = (15 - ip) * 64;
    const int b   = blockIdx.y >> 4;
    const int h   = blockIdx.y & 15;

    const __bf16* qp = qkv + (size_t)b * SEQ_T * QS + h * DKH;
    const __bf16* kp = qp + D_MODEL;
    const __bf16* vp = qp + 2 * D_MODEL;
    __bf16* yp = y + (size_t)b * SEQ_T * D_MODEL + h * DKH;

    bf16x8 qfA[2], qfB[2];
    {
        const int qrA = q0A + wave * 16 + r;
        const int qrB = q0B + wave * 16 + r;
        #pragma unroll
        for (int kc = 0; kc < 2; ++kc) {
            qfA[kc] = *(const bf16x8*)(qp + (size_t)qrA * QS + kc * 32 + kb * 8);
            qfB[kc] = *(const bf16x8*)(qp + (size_t)qrB * QS + kc * 32 + kb * 8);
        }
    }

    AttnState stA, stB;
    #pragma unroll
    for (int rg = 0; rg < 4; ++rg) {
        stA.m[rg] = -INFINITY; stA.l[rg] = 0.0f;
        stB.m[rg] = -INFINITY; stB.l[rg] = 0.0f;
    }
    #pragma unroll
    for (int n = 0; n < 4; ++n) { stA.yacc[n] = {}; stB.yacc[n] = {}; }

    const int skey = tid >> 2;          // 0..63
    const int sg16 = (tid & 3) * 16;    // 0,16,32,48
    const int swz0 = ((sg16 >> 3) & 7) * 8;
    const int swz1 = (((sg16 + 8) >> 3) & 7) * 8;

    const int ntiles = 16 - ip;

    // prologue: stage tile 0 regs -> buf 0
    bf16x8 kr0, kr1, vr0, vr1;
    {
        const size_t go = (size_t)skey * QS;
        kr0 = *(const bf16x8*)(kp + go + sg16);
        kr1 = *(const bf16x8*)(kp + go + sg16 + 8);
        vr0 = *(const bf16x8*)(vp + go + sg16);
        vr1 = *(const bf16x8*)(vp + go + sg16 + 8);
    }
    *(bf16x8*)&K_lds[0][skey][sg16]     = kr0;
    *(bf16x8*)&K_lds[0][skey][sg16 + 8] = kr1;
    #pragma unroll
    for (int j = 0; j < 8; ++j) V_lds[0][sg16 + j][skey ^ swz0]     = vr0[j];
    #pragma unroll
    for (int j = 0; j < 8; ++j) V_lds[0][sg16 + 8 + j][skey ^ swz1] = vr1[j];
    __syncthreads();

    int cur = 0;
    for (int kt = 0; kt < ntiles; ++kt) {
        const bool has_next = (kt + 1 < ntiles);
        // issue next tile's loads early (latency hides under compute)
        if (has_next) {
            const size_t go = (size_t)((kt + 1) * 64 + skey) * QS;
            kr0 = *(const bf16x8*)(kp + go + sg16);
            kr1 = *(const bf16x8*)(kp + go + sg16 + 8);
            vr0 = *(const bf16x8*)(vp + go + sg16);
            vr1 = *(const bf16x8*)(vp + go + sg16 + 8);
        }

        if (kt == ntiles - 1)
            attn_tile_step<true >(stB, qfB, q0B, kt, wave, r, kb, K_lds[cur], V_lds[cur], P_lds[wave]);
        else
            attn_tile_step<false>(stB, qfB, q0B, kt, wave, r, kb, K_lds[cur], V_lds[cur], P_lds[wave]);
        if (kt <= ip) {
            if (kt == ip)
                attn_tile_step<true >(stA, qfA, q0A, kt, wave, r, kb, K_lds[cur], V_lds[cur], P_lds[wave]);
            else
                attn_tile_step<false>(stA, qfA, q0A, kt, wave, r, kb, K_lds[cur], V_lds[cur], P_lds[wave]);
        }

        // write staged regs to the other buffer (last read of buf^1 was
        // iteration kt-1, separated by the barrier below from iteration kt-1)
        if (has_next) {
            const int nb = cur ^ 1;
            *(bf16x8*)&K_lds[nb][skey][sg16]     = kr0;
            *(bf16x8*)&K_lds[nb][skey][sg16 + 8] = kr1;
            #pragma unroll
            for (int j = 0; j < 8; ++j) V_lds[nb][sg16 + j][skey ^ swz0]     = vr0[j];
            #pragma unroll
            for (int j = 0; j < 8; ++j) V_lds[nb][sg16 + 8 + j][skey ^ swz1] = vr1[j];
        }
        __syncthreads();
        cur ^= 1;
    }

    float invA[4], invB[4];
    #pragma unroll
    for (int rg = 0; rg < 4; ++rg) {
        invA[rg] = 1.0f / stA.l[rg];
        invB[rg] = 1.0f / stB.l[rg];
    }
    #pragma unroll
    for (int n = 0; n < 4; ++n) {
        #pragma unroll
        for (int rg = 0; rg < 4; ++rg) {
            const int rowA = q0A + wave * 16 + kb * 4 + rg;
            const int rowB = q0B + wave * 16 + kb * 4 + rg;
            yp[(size_t)rowA * D_MODEL + n * 16 + r] = (__bf16)(stA.yacc[n][rg] * invA[rg]);
            yp[(size_t)rowB * D_MODEL + n * 16 + r] = (__bf16)(stB.yacc[n][rg] * invB[rg]);
        }
    }
}

// ---------------------------------------------------------------------------
extern "C" void kernel_launch(void* const* d_in, const int* in_sizes, int n_in,
                              void* d_out, int out_size, void* d_ws, size_t ws_size,
                              hipStream_t stream)
{
    const int*   x       = (const int*)  d_in[0];
    const float* inp_emb = (const float*)d_in[1];
    const float* pos_emb = (const float*)d_in[2];
    const float* wq = (const float*)d_in[3];
    const float* bq = (const float*)d_in[4];
    const float* wk = (const float*)d_in[5];
    const float* bk = (const float*)d_in[6];
    const float* wv = (const float*)d_in[7];
    const float* bv = (const float*)d_in[8];
    const float* wo = (const float*)d_in[9];
    const float* bo = (const float*)d_in[10];
    const float* w1 = (const float*)d_in[11];
    const float* b1 = (const float*)d_in[12];
    const float* w2 = (const float*)d_in[13];
    const float* b2 = (const float*)d_in[14];
    const float* ln1_s = (const float*)d_in[15];
    const float* ln1_b = (const float*)d_in[16];
    const float* ln2_s = (const float*)d_in[17];
    const float* ln2_b = (const float*)d_in[18];
    const float* lno_s = (const float*)d_in[19];
    const float* lno_b = (const float*)d_in[20];
    const float* w_out = (const float*)d_in[21];

    const int M = BATCH * SEQ_T;                 // 2048
    const size_t MB = 1u << 20;

    char* w = (char*)d_ws;
    __bf16* h     = (__bf16*)(w + 0);            // 4MB (bf16 residual stream)
    __bf16* xn    = (__bf16*)(w + 8  * MB);      // 4MB
    __bf16* yb    = (__bf16*)(w + 12 * MB);      // 4MB
    __bf16* sh    = (__bf16*)(w + 16 * MB);      // qkv/mid 16MB
    __bf16* wqkvT = (__bf16*)(w + 32 * MB);      // 6MB
    __bf16* woT   = (__bf16*)(w + 38 * MB);      // 2MB
    __bf16* w1T   = (__bf16*)(w + 40 * MB);      // 8MB
    __bf16* w2T   = (__bf16*)(w + 48 * MB);      // 8MB
    float*  bqkv  = (float*) (w + 56 * MB);      // 12KB
    __bf16* woutT = (__bf16*)(w + 57 * MB);      // 62.5MB

    embed_kernel<<<dim3(M * D_MODEL / 1024), 256, 0, stream>>>(x, inp_emb, pos_emb, h);

    for (int i = 0; i < NLAYERS; ++i) {
        const size_t wOff  = (size_t)i * D_MODEL * D_MODEL;
        const size_t w1Off = (size_t)i * D_MODEL * DFF_;

        // merged: LN1 + weight prep
        prep_ln_kernel<<<dim3(2048 + 6156), 256, 0, stream>>>(
            h, ln1_s + i * D_MODEL, ln1_b + i * D_MODEL, xn,
            wq + wOff, wk + wOff, wv + wOff, wo + wOff, w1 + w1Off, w2 + w1Off,
            bq + i * D_MODEL, bk + i * D_MODEL, bv + i * D_MODEL,
            wqkvT, woT, w1T, w2T, bqkv);

        gemm_bt<64, 0, __bf16><<<dim3(M / 128, 3 * D_MODEL / 64), 256, 0, stream>>>(
            xn, wqkvT, bqkv, nullptr, sh, M, 3 * D_MODEL, D_MODEL);
        attn_mfma_kernel<<<dim3(8, BATCH * N_HEADS), 256, 0, stream>>>(sh, yb);
        gemm_bt<64, 1, __bf16><<<dim3(M / 128, D_MODEL / 64), 256, 0, stream>>>(
            yb, woT, bo + i * D_MODEL, h, h, M, D_MODEL, D_MODEL);
        layernorm_kernel<<<dim3(M), 256, 0, stream>>>(h, ln2_s + i * D_MODEL, ln2_b + i * D_MODEL, xn);
        gemm_bt<128, 2, __bf16><<<dim3(M / 128, DFF_ / 128), 256, 0, stream>>>(
            xn, w1T, b1 + i * DFF_, nullptr, sh, M, DFF_, D_MODEL);
        gemm_bt<64, 1, __bf16><<<dim3(M / 128, D_MODEL / 64), 256, 0, stream>>>(
            sh, w2T, b2 + i * D_MODEL, h, h, M, D_MODEL, DFF_);
    }

    // w_out transpose + final LN in one dispatch, right before logits
    // (woutT stays L3-resident for the GEMM -- r12 lesson)
    wout_ln_kernel<<<dim3(16000 + 2048), 256, 0, stream>>>(
        w_out, woutT, h, lno_s, lno_b, xn);
    gemm_bt<128, 0, float, true><<<dim3(M / 128, VOCAB / 128), 256, 0, stream>>>(
        xn, woutT, nullptr, nullptr, (float*)d_out, M, VOCAB, D_MODEL);
}

// Round 14
// 1619.665 us; speedup vs baseline: 1.0202x; 1.0202x over previous
//
#include <hip/hip_runtime.h>
#include <cmath>

#define D_MODEL 1024
#define N_HEADS 16
#define DKH     64
#define SEQ_T   1024
#define BATCH   2
#define VOCAB   32000
#define DFF_    4096
#define NLAYERS 8

typedef __bf16 bf16x8 __attribute__((ext_vector_type(8)));
typedef __bf16 bf16x4v __attribute__((ext_vector_type(4)));
typedef float  f32x4  __attribute__((ext_vector_type(4)));

__device__ __forceinline__ float gelu_f(float x) {
    return 0.5f * x * (1.0f + erff(x * 0.70710678118654752f));
}

__device__ __forceinline__ void gload_lds16(const void* g, void* l) {
    __builtin_amdgcn_global_load_lds(
        (const __attribute__((address_space(1))) void*)g,
        (__attribute__((address_space(3))) void*)l, 16, 0, 0);
}

// ---------------------------------------------------------------------------
// Embedding: h (f32) = inp_emb[x] + pos_emb. 4 elems/thread, float4 I/O.
// ---------------------------------------------------------------------------
__global__ __launch_bounds__(256) void embed_kernel(
    const int* __restrict__ x, const float* __restrict__ inp_emb,
    const float* __restrict__ pos_emb, float* __restrict__ h)
{
    const int idx = (blockIdx.x * 256 + threadIdx.x) * 4;
    const int bt  = idx >> 10;
    const int d   = idx & 1023;
    const int t   = bt & (SEQ_T - 1);
    const int tok = x[bt];
    const float4 a = *(const float4*)(inp_emb + (size_t)tok * D_MODEL + d);
    const float4 b = *(const float4*)(pos_emb + (size_t)t * D_MODEL + d);
    float4 o;
    o.x = a.x + b.x;
    o.y = a.y + b.y;
    o.z = a.z + b.z;
    o.w = a.w + b.w;
    *(float4*)(h + idx) = o;
}

// ---------------------------------------------------------------------------
// LayerNorm body (D=1024), f32 in, bf16 out. One 256-thr block per row.
// ---------------------------------------------------------------------------
__device__ __forceinline__ void ln_row(
    const float* __restrict__ x, const float* __restrict__ sc,
    const float* __restrict__ bi, __bf16* __restrict__ o, int row, int tid)
{
    const int c = tid * 4;
    const float4 v = *(const float4*)(x + (size_t)row * D_MODEL + c);
    float sum = v.x + v.y + v.z + v.w;
    float sq  = v.x * v.x + v.y * v.y + v.z * v.z + v.w * v.w;
    #pragma unroll
    for (int off = 32; off > 0; off >>= 1) {
        sum += __shfl_xor(sum, off);
        sq  += __shfl_xor(sq, off);
    }
    __shared__ float ssum[4], ssq[4];
    const int wave = tid >> 6, lane = tid & 63;
    if (lane == 0) { ssum[wave] = sum; ssq[wave] = sq; }
    __syncthreads();
    sum = ssum[0] + ssum[1] + ssum[2] + ssum[3];
    sq  = ssq[0]  + ssq[1]  + ssq[2]  + ssq[3];
    const float mu  = sum * (1.0f / D_MODEL);
    const float var = sq * (1.0f / D_MODEL) - mu * mu;
    const float rs  = rsqrtf(var + 1e-5f);
    const float4 s4 = *(const float4*)(sc + c);
    const float4 b4 = *(const float4*)(bi + c);
    bf16x4v ov;
    ov[0] = (__bf16)((v.x - mu) * rs * s4.x + b4.x);
    ov[1] = (__bf16)((v.y - mu) * rs * s4.y + b4.y);
    ov[2] = (__bf16)((v.z - mu) * rs * s4.z + b4.z);
    ov[3] = (__bf16)((v.w - mu) * rs * s4.w + b4.w);
    *(bf16x4v*)(o + (size_t)row * D_MODEL + c) = ov;
}

__global__ __launch_bounds__(256) void layernorm_kernel(
    const float* __restrict__ x, const float* __restrict__ sc,
    const float* __restrict__ bi, __bf16* __restrict__ o)
{
    ln_row(x, sc, bi, o, blockIdx.x, threadIdx.x);
}

// ---------------------------------------------------------------------------
// w_out transpose: f32 [1024][32000] -> bf16 [32000][1024]. 32x64 tiles,
// bf16x8 writes. Launched RIGHT BEFORE the logits GEMM so woutT is
// L3-resident when the GEMM reads it (r8 vs r11: 185 vs 241 us on logits).
// ---------------------------------------------------------------------------
__global__ __launch_bounds__(256) void wout_tr_kernel(
    const float* __restrict__ in, __bf16* __restrict__ out)
{
    __shared__ __bf16 tile[32][72];
    const int tid = threadIdx.x;
    const int t   = blockIdx.x;
    const int kb0 = (t & 31) * 32;
    const int nb0 = (t >> 5) * 64;
    {
        const int rr = tid >> 3, c8 = (tid & 7) * 8;
        const float* p = in + (size_t)(kb0 + rr) * VOCAB + nb0 + c8;
        const float4 v0 = *(const float4*)p;
        const float4 v1 = *(const float4*)(p + 4);
        tile[rr][c8 + 0] = (__bf16)v0.x;
        tile[rr][c8 + 1] = (__bf16)v0.y;
        tile[rr][c8 + 2] = (__bf16)v0.z;
        tile[rr][c8 + 3] = (__bf16)v0.w;
        tile[rr][c8 + 4] = (__bf16)v1.x;
        tile[rr][c8 + 5] = (__bf16)v1.y;
        tile[rr][c8 + 6] = (__bf16)v1.z;
        tile[rr][c8 + 7] = (__bf16)v1.w;
    }
    __syncthreads();
    {
        const int cc = tid >> 2, k8 = (tid & 3) * 8;
        bf16x8 ov;
        #pragma unroll
        for (int e = 0; e < 8; ++e) ov[e] = tile[k8 + e][cc];
        *(bf16x8*)(out + (size_t)(nb0 + cc) * D_MODEL + kb0 + k8) = ov;
    }
}

// ---------------------------------------------------------------------------
// Merged per-layer dispatch: LN1 (blocks 0..2047) + 6 weight transposes
// (f32 [K][N] -> bf16 [N][K], 32x64 tiles, bf16x8 writes) + qkv bias concat.
// ---------------------------------------------------------------------------
__global__ __launch_bounds__(256) void prep_ln_kernel(
    const float* __restrict__ h, const float* __restrict__ ln_s,
    const float* __restrict__ ln_b, __bf16* __restrict__ xn,
    const float* __restrict__ wq, const float* __restrict__ wk,
    const float* __restrict__ wv, const float* __restrict__ wo,
    const float* __restrict__ w1, const float* __restrict__ w2,
    const float* __restrict__ bq, const float* __restrict__ bk,
    const float* __restrict__ bv,
    __bf16* __restrict__ wqkvT, __bf16* __restrict__ woT,
    __bf16* __restrict__ w1T, __bf16* __restrict__ w2T,
    float* __restrict__ bqkv)
{
    const int tid = threadIdx.x;
    const int b   = blockIdx.x;

    if (b < 2048) {                       // LN1
        ln_row(h, ln_s, ln_b, xn, b, tid);
        return;
    }
    const int pb = b - 2048;
    if (pb >= 6144) {                     // bias concat (12 blocks)
        const int j = (pb - 6144) * 256 + tid;
        bqkv[j] = (j < 1024) ? bq[j] : (j < 2048 ? bk[j - 1024] : bv[j - 2048]);
        return;
    }

    // 32(K) x 64(N) transpose tile
    __shared__ __bf16 tile[32][72];
    const float* in;
    __bf16* out;
    int K, N, kb0, nb0;
    if (pb < 2048) {                      // wq/wk/wv/wo: 512 tiles each
        const int w = pb >> 9, t = pb & 511;
        K = 1024; N = 1024; kb0 = (t >> 4) * 32; nb0 = (t & 15) * 64;
        in  = (w == 0) ? wq : (w == 1) ? wk : (w == 2) ? wv : wo;
        out = (w == 3) ? woT : wqkvT + (size_t)w * 1024 * 1024;
    } else if (pb < 4096) {               // w1: K=1024, N=4096
        const int t = pb - 2048;
        K = 1024; N = 4096; kb0 = (t >> 6) * 32; nb0 = (t & 63) * 64;
        in = w1; out = w1T;
    } else {                              // w2: K=4096, N=1024
        const int t = pb - 4096;
        K = 4096; N = 1024; kb0 = (t >> 4) * 32; nb0 = (t & 15) * 64;
        in = w2; out = w2T;
    }

    {   // read: 32 rows x 64 cols, 8 f32 per thread
        const int rr = tid >> 3, c8 = (tid & 7) * 8;
        const float* p = in + (size_t)(kb0 + rr) * N + nb0 + c8;
        const float4 v0 = *(const float4*)p;
        const float4 v1 = *(const float4*)(p + 4);
        tile[rr][c8 + 0] = (__bf16)v0.x;
        tile[rr][c8 + 1] = (__bf16)v0.y;
        tile[rr][c8 + 2] = (__bf16)v0.z;
        tile[rr][c8 + 3] = (__bf16)v0.w;
        tile[rr][c8 + 4] = (__bf16)v1.x;
        tile[rr][c8 + 5] = (__bf16)v1.y;
        tile[rr][c8 + 6] = (__bf16)v1.z;
        tile[rr][c8 + 7] = (__bf16)v1.w;
    }
    __syncthreads();
    {   // write: 64 cols x 32 k, bf16x8 (16B) per thread
        const int cc = tid >> 2, k8 = (tid & 3) * 8;
        bf16x8 ov;
        #pragma unroll
        for (int e = 0; e < 8; ++e) ov[e] = tile[k8 + e][cc];
        *(bf16x8*)(out + (size_t)(nb0 + cc) * K + kb0 + k8) = ov;
    }
}

// ---------------------------------------------------------------------------
// GEMM: C[M,N] = epi(A[M,K] @ Bt[N,K]^T + bias). bf16 in, f32 acc.
// Single-buffered m97 structure: 128 x BN_T tile, BK=64, global_load_lds
// staging, XOR-granule swizzle both sides, M-fast grid + XCD chunking.
// NT: direct nontemporal C stores (streaming output).
// ---------------------------------------------------------------------------
template <int BN_T, int EPI, typename OutT, bool NT = false>
__global__ __launch_bounds__(256) void gemm_bt(
    const __bf16* __restrict__ A, const __bf16* __restrict__ Bt,
    const float* __restrict__ bias, const float* __restrict__ res,
    OutT* __restrict__ C, int M, int N, int K)
{
    constexpr int NF  = BN_T / 32;
    constexpr int NCB = BN_T / 8;
    __shared__ __bf16 As[128 * 64];
    __shared__ __bf16 Bs[BN_T * 64];

    const int tid  = threadIdx.x;
    const int wave = tid >> 6;
    const int lane = tid & 63;
    const int r    = lane & 15;
    const int kb   = lane >> 4;
    const int wm   = wave >> 1;
    const int wn   = wave & 1;

    const int ntm = gridDim.x;
    const int nwg = ntm * gridDim.y;
    int bid = blockIdx.y * ntm + blockIdx.x;
    if ((nwg & 7) == 0) bid = (bid & 7) * (nwg >> 3) + (bid >> 3);
    const int bm = (bid % ntm) * 128;
    const int bn = (bid / ntm) * BN_T;

    const int srow = lane >> 3;
    const int sg   = lane & 7;

    f32x4 acc[4][NF] = {};

    for (int k0 = 0; k0 < K; k0 += 64) {
        #pragma unroll
        for (int i = 0; i < 4; ++i) {
            const int c    = i * 4 + wave;
            const int row  = c * 8 + srow;
            const int scol = (sg ^ (row & 7)) * 8;
            gload_lds16(A + (size_t)(bm + row) * K + k0 + scol, &As[c * 512]);
        }
        #pragma unroll
        for (int i = 0; i < NCB / 4; ++i) {
            const int c    = i * 4 + wave;
            const int row  = c * 8 + srow;
            const int scol = (sg ^ (row & 7)) * 8;
            gload_lds16(Bt + (size_t)(bn + row) * K + k0 + scol, &Bs[c * 512]);
        }
        __syncthreads();

        #pragma unroll
        for (int s = 0; s < 2; ++s) {
            bf16x8 af[4];
            #pragma unroll
            for (int m = 0; m < 4; ++m) {
                const int row = wm * 64 + m * 16 + r;
                const int g   = (s * 4 + kb) ^ (row & 7);
                af[m] = *(const bf16x8*)&As[row * 64 + g * 8];
            }
            #pragma unroll
            for (int n = 0; n < NF; ++n) {
                const int row = wn * (NF * 16) + n * 16 + r;
                const int g   = (s * 4 + kb) ^ (row & 7);
                const bf16x8 bfr = *(const bf16x8*)&Bs[row * 64 + g * 8];
                #pragma unroll
                for (int m = 0; m < 4; ++m)
                    acc[m][n] = __builtin_amdgcn_mfma_f32_16x16x32_bf16(af[m], bfr, acc[m][n], 0, 0, 0);
            }
        }
        __syncthreads();
    }

    #pragma unroll
    for (int m = 0; m < 4; ++m) {
        const int row = bm + wm * 64 + m * 16 + kb * 4;
        #pragma unroll
        for (int n = 0; n < NF; ++n) {
            const int col = bn + wn * (NF * 16) + n * 16 + r;
            const float bv = bias ? bias[col] : 0.0f;
            #pragma unroll
            for (int rg = 0; rg < 4; ++rg) {
                float v = acc[m][n][rg] + bv;
                if constexpr (EPI == 1) v += res[(size_t)(row + rg) * N + col];
                if constexpr (EPI == 2) v = gelu_f(v);
                if constexpr (NT) {
                    __builtin_nontemporal_store((OutT)v, &C[(size_t)(row + rg) * N + col]);
                } else {
                    C[(size_t)(row + rg) * N + col] = (OutT)v;
                }
            }
        }
    }
}

// ---------------------------------------------------------------------------
// Balanced MFMA flash attention (causal), bf16 packed qkv (row stride 3072).
// One block = (b, h, query-tile PAIR {i, 15-i}), 4 waves x 16 q per tile.
// Diagonal-only masking + defer-max (THR=8) + T14 async-STAGE split.
// ---------------------------------------------------------------------------
struct AttnState {
    float m[4];
    float l[4];
    f32x4 yacc[4];
};

template <bool MASK>
__device__ __forceinline__ void attn_tile_step(
    AttnState& st, const bf16x8 (&qf)[2], int q0, int kt,
    int wave, int r, int kb,
    const __bf16 (*K_lds)[72], const __bf16 (*V_lds)[72],
    __bf16 (*P_row)[72])
{
    f32x4 sacc[4] = {};
    #pragma unroll
    for (int kc = 0; kc < 2; ++kc) {
        #pragma unroll
        for (int g = 0; g < 4; ++g) {
            const bf16x8 kf = *(const bf16x8*)&K_lds[g * 16 + r][kc * 32 + kb * 8];
            sacc[g] = __builtin_amdgcn_mfma_f32_16x16x32_bf16(qf[kc], kf, sacc[g], 0, 0, 0);
        }
    }

    float s[4][4], p[4][4];
    #pragma unroll
    for (int g = 0; g < 4; ++g) {
        #pragma unroll
        for (int rg = 0; rg < 4; ++rg) {
            if constexpr (MASK) {
                const int key = kt * 64 + g * 16 + r;
                const int qq  = q0 + wave * 16 + kb * 4 + rg;
                s[g][rg] = (key <= qq) ? sacc[g][rg] * 0.125f : -INFINITY;
            } else {
                s[g][rg] = sacc[g][rg] * 0.125f;
            }
        }
    }

    float mt[4];
    #pragma unroll
    for (int rg = 0; rg < 4; ++rg)
        mt[rg] = fmaxf(fmaxf(s[0][rg], s[1][rg]), fmaxf(s[2][rg], s[3][rg]));
    #pragma unroll
    for (int off = 1; off < 16; off <<= 1) {
        #pragma unroll
        for (int rg = 0; rg < 4; ++rg) mt[rg] = fmaxf(mt[rg], __shfl_xor(mt[rg], off));
    }

    bool grow = false;
    #pragma unroll
    for (int rg = 0; rg < 4; ++rg) grow |= (mt[rg] > st.m[rg] + 8.0f);
    if (__any(grow)) {
        #pragma unroll
        for (int rg = 0; rg < 4; ++rg) {
            const float mn   = fmaxf(st.m[rg], mt[rg]);
            const float corr = __expf(st.m[rg] - mn);
            st.l[rg] *= corr;
            st.m[rg]  = mn;
            #pragma unroll
            for (int n = 0; n < 4; ++n) st.yacc[n][rg] *= corr;
        }
    }

    float psum[4];
    #pragma unroll
    for (int rg = 0; rg < 4; ++rg) {
        psum[rg] = 0.0f;
        #pragma unroll
        for (int g = 0; g < 4; ++g) {
            p[g][rg] = __expf(s[g][rg] - st.m[rg]);
            psum[rg] += p[g][rg];
        }
    }
    #pragma unroll
    for (int off = 1; off < 16; off <<= 1) {
        #pragma unroll
        for (int rg = 0; rg < 4; ++rg) psum[rg] += __shfl_xor(psum[rg], off);
    }
    #pragma unroll
    for (int rg = 0; rg < 4; ++rg) st.l[rg] += psum[rg];

    #pragma unroll
    for (int g = 0; g < 4; ++g) {
        #pragma unroll
        for (int rg = 0; rg < 4; ++rg)
            P_row[kb * 4 + rg][g * 16 + r] = (__bf16)p[g][rg];
    }
    const bf16x8 pa0 = *(const bf16x8*)&P_row[r][kb * 8];
    const bf16x8 pa1 = *(const bf16x8*)&P_row[r][32 + kb * 8];

    #pragma unroll
    for (int n = 0; n < 4; ++n) {
        const int vrow = n * 16 + r;
        const int swz  = (vrow >> 3) & 7;
        const bf16x8 vf0 = *(const bf16x8*)&V_lds[vrow][(kb ^ swz) * 8];
        st.yacc[n] = __builtin_amdgcn_mfma_f32_16x16x32_bf16(pa0, vf0, st.yacc[n], 0, 0, 0);
    }
    #pragma unroll
    for (int n = 0; n < 4; ++n) {
        const int vrow = n * 16 + r;
        const int swz  = (vrow >> 3) & 7;
        const bf16x8 vf1 = *(const bf16x8*)&V_lds[vrow][((kb + 4) ^ swz) * 8];
        st.yacc[n] = __builtin_amdgcn_mfma_f32_16x16x32_bf16(pa1, vf1, st.yacc[n], 0, 0, 0);
    }
}

__global__ __launch_bounds__(256) void attn_mfma_kernel(
    const __bf16* __restrict__ qkv, __bf16* __restrict__ y)
{
    constexpr int QS = 3 * D_MODEL;
    __shared__ __align__(16) __bf16 K_lds[64][72];
    __shared__ __align__(16) __bf16 V_lds[64][72];
    __shared__ __align__(16) __bf16 P_lds[4][16][72];

    const int tid  = threadIdx.x;
    const int wave = tid >> 6;
    const int lane = tid & 63;
    const int r    = lane & 15;
    const int kb   = lane >> 4;

    const int ip  = blockIdx.x;           // 0..7
    const int q0A = ip * 64;
    const int q0B = (15 - ip) * 64;
    const int b   = blockIdx.y >> 4;
    const int h   = blockIdx.y & 15;

    const __bf16* qp = qkv + (size_t)b * SEQ_T * QS + h * DKH;
    const __bf16* kp = qp + D_MODEL;
    const __bf16* vp = qp + 2 * D_MODEL;
    __bf16* yp = y + (size_t)b * SEQ_T * D_MODEL + h * DKH;

    bf16x8 qfA[2], qfB[2];
    {
        const int qrA = q0A + wave * 16 + r;
        const int qrB = q0B + wave * 16 + r;
        #pragma unroll
        for (int kc = 0; kc < 2; ++kc) {
            qfA[kc] = *(const bf16x8*)(qp + (size_t)qrA * QS + kc * 32 + kb * 8);
            qfB[kc] = *(const bf16x8*)(qp + (size_t)qrB * QS + kc * 32 + kb * 8);
        }
    }

    AttnState stA, stB;
    #pragma unroll
    for (int rg = 0; rg < 4; ++rg) {
        stA.m[rg] = -INFINITY; stA.l[rg] = 0.0f;
        stB.m[rg] = -INFINITY; stB.l[rg] = 0.0f;
    }
    #pragma unroll
    for (int n = 0; n < 4; ++n) { stA.yacc[n] = {}; stB.yacc[n] = {}; }

    const int skey = tid >> 2;          // 0..63
    const int sg16 = (tid & 3) * 16;    // 0,16,32,48
    const int swz0 = ((sg16 >> 3) & 7) * 8;
    const int swz1 = (((sg16 + 8) >> 3) & 7) * 8;

    const int ntiles = 16 - ip;

    // prologue: stage tile 0 into registers
    bf16x8 kr0, kr1, vr0, vr1;
    {
        const size_t go = (size_t)skey * QS;
        kr0 = *(const bf16x8*)(kp + go + sg16);
        kr1 = *(const bf16x8*)(kp + go + sg16 + 8);
        vr0 = *(const bf16x8*)(vp + go + sg16);
        vr1 = *(const bf16x8*)(vp + go + sg16 + 8);
    }

    for (int kt = 0; kt < ntiles; ++kt) {
        // write staged registers to LDS
        *(bf16x8*)&K_lds[skey][sg16]     = kr0;
        *(bf16x8*)&K_lds[skey][sg16 + 8] = kr1;
        #pragma unroll
        for (int j = 0; j < 8; ++j)
            V_lds[sg16 + j][skey ^ swz0] = vr0[j];
        #pragma unroll
        for (int j = 0; j < 8; ++j)
            V_lds[sg16 + 8 + j][skey ^ swz1] = vr1[j];
        __syncthreads();

        // issue next tile's loads early (latency hides under compute)
        if (kt + 1 < ntiles) {
            const size_t go = (size_t)((kt + 1) * 64 + skey) * QS;
            kr0 = *(const bf16x8*)(kp + go + sg16);
            kr1 = *(const bf16x8*)(kp + go + sg16 + 8);
            vr0 = *(const bf16x8*)(vp + go + sg16);
            vr1 = *(const bf16x8*)(vp + go + sg16 + 8);
        }

        if (kt == ntiles - 1)
            attn_tile_step<true >(stB, qfB, q0B, kt, wave, r, kb, K_lds, V_lds, P_lds[wave]);
        else
            attn_tile_step<false>(stB, qfB, q0B, kt, wave, r, kb, K_lds, V_lds, P_lds[wave]);
        if (kt <= ip) {
            if (kt == ip)
                attn_tile_step<true >(stA, qfA, q0A, kt, wave, r, kb, K_lds, V_lds, P_lds[wave]);
            else
                attn_tile_step<false>(stA, qfA, q0A, kt, wave, r, kb, K_lds, V_lds, P_lds[wave]);
        }
        __syncthreads();
    }

    float invA[4], invB[4];
    #pragma unroll
    for (int rg = 0; rg < 4; ++rg) {
        invA[rg] = 1.0f / stA.l[rg];
        invB[rg] = 1.0f / stB.l[rg];
    }
    #pragma unroll
    for (int n = 0; n < 4; ++n) {
        #pragma unroll
        for (int rg = 0; rg < 4; ++rg) {
            const int rowA = q0A + wave * 16 + kb * 4 + rg;
            const int rowB = q0B + wave * 16 + kb * 4 + rg;
            yp[(size_t)rowA * D_MODEL + n * 16 + r] = (__bf16)(stA.yacc[n][rg] * invA[rg]);
            yp[(size_t)rowB * D_MODEL + n * 16 + r] = (__bf16)(stB.yacc[n][rg] * invB[rg]);
        }
    }
}

// ---------------------------------------------------------------------------
extern "C" void kernel_launch(void* const* d_in, const int* in_sizes, int n_in,
                              void* d_out, int out_size, void* d_ws, size_t ws_size,
                              hipStream_t stream)
{
    const int*   x       = (const int*)  d_in[0];
    const float* inp_emb = (const float*)d_in[1];
    const float* pos_emb = (const float*)d_in[2];
    const float* wq = (const float*)d_in[3];
    const float* bq = (const float*)d_in[4];
    const float* wk = (const float*)d_in[5];
    const float* bk = (const float*)d_in[6];
    const float* wv = (const float*)d_in[7];
    const float* bv = (const float*)d_in[8];
    const float* wo = (const float*)d_in[9];
    const float* bo = (const float*)d_in[10];
    const float* w1 = (const float*)d_in[11];
    const float* b1 = (const float*)d_in[12];
    const float* w2 = (const float*)d_in[13];
    const float* b2 = (const float*)d_in[14];
    const float* ln1_s = (const float*)d_in[15];
    const float* ln1_b = (const float*)d_in[16];
    const float* ln2_s = (const float*)d_in[17];
    const float* ln2_b = (const float*)d_in[18];
    const float* lno_s = (const float*)d_in[19];
    const float* lno_b = (const float*)d_in[20];
    const float* w_out = (const float*)d_in[21];

    const int M = BATCH * SEQ_T;                 // 2048
    const size_t MB = 1u << 20;

    char* w = (char*)d_ws;
    float*  h     = (float*) (w + 0);            // 8MB
    __bf16* xn    = (__bf16*)(w + 8  * MB);      // 4MB
    __bf16* yb    = (__bf16*)(w + 12 * MB);      // 4MB
    __bf16* sh    = (__bf16*)(w + 16 * MB);      // qkv/mid 16MB
    __bf16* wqkvT = (__bf16*)(w + 32 * MB);      // 6MB
    __bf16* woT   = (__bf16*)(w + 38 * MB);      // 2MB
    __bf16* w1T   = (__bf16*)(w + 40 * MB);      // 8MB
    __bf16* w2T   = (__bf16*)(w + 48 * MB);      // 8MB
    float*  bqkv  = (float*) (w + 56 * MB);      // 12KB
    __bf16* woutT = (__bf16*)(w + 57 * MB);      // 62.5MB

    embed_kernel<<<dim3(M * D_MODEL / 1024), 256, 0, stream>>>(x, inp_emb, pos_emb, h);

    for (int i = 0; i < NLAYERS; ++i) {
        const size_t wOff  = (size_t)i * D_MODEL * D_MODEL;
        const size_t w1Off = (size_t)i * D_MODEL * DFF_;

        // merged: LN1 + weight prep
        prep_ln_kernel<<<dim3(2048 + 6156), 256, 0, stream>>>(
            h, ln1_s + i * D_MODEL, ln1_b + i * D_MODEL, xn,
            wq + wOff, wk + wOff, wv + wOff, wo + wOff, w1 + w1Off, w2 + w1Off,
            bq + i * D_MODEL, bk + i * D_MODEL, bv + i * D_MODEL,
            wqkvT, woT, w1T, w2T, bqkv);

        gemm_bt<64, 0, __bf16><<<dim3(M / 128, 3 * D_MODEL / 64), 256, 0, stream>>>(
            xn, wqkvT, bqkv, nullptr, sh, M, 3 * D_MODEL, D_MODEL);
        attn_mfma_kernel<<<dim3(8, BATCH * N_HEADS), 256, 0, stream>>>(sh, yb);
        gemm_bt<64, 1, float><<<dim3(M / 128, D_MODEL / 64), 256, 0, stream>>>(
            yb, woT, bo + i * D_MODEL, h, h, M, D_MODEL, D_MODEL);
        layernorm_kernel<<<dim3(M), 256, 0, stream>>>(h, ln2_s + i * D_MODEL, ln2_b + i * D_MODEL, xn);
        gemm_bt<128, 2, __bf16><<<dim3(M / 128, DFF_ / 128), 256, 0, stream>>>(
            xn, w1T, b1 + i * DFF_, nullptr, sh, M, DFF_, D_MODEL);
        gemm_bt<64, 1, float><<<dim3(M / 128, D_MODEL / 64), 256, 0, stream>>>(
            sh, w2T, b2 + i * D_MODEL, h, h, M, D_MODEL, DFF_);
    }

    // w_out transpose RIGHT BEFORE logits: woutT stays L3-resident for the GEMM
    wout_tr_kernel<<<dim3(16000), 256, 0, stream>>>(w_out, woutT);
    layernorm_kernel<<<dim3(M), 256, 0, stream>>>(h, lno_s, lno_b, xn);
    gemm_bt<128, 0, float, true><<<dim3(M / 128, VOCAB / 128), 256, 0, stream>>>(
        xn, woutT, nullptr, nullptr, (float*)d_out, M, VOCAB, D_MODEL);
}

// Round 15
// 1491.300 us; speedup vs baseline: 1.1080x; 1.0861x over previous
//
#include <hip/hip_runtime.h>
#include <cmath>

#define D_MODEL 1024
#define N_HEADS 16
#define DKH     64
#define SEQ_T   1024
#define BATCH   2
#define VOCAB   32000
#define DFF_    4096
#define NLAYERS 8

typedef __bf16 bf16x8 __attribute__((ext_vector_type(8)));
typedef __bf16 bf16x4v __attribute__((ext_vector_type(4)));
typedef float  f32x4  __attribute__((ext_vector_type(4)));

__device__ __forceinline__ float gelu_f(float x) {
    return 0.5f * x * (1.0f + erff(x * 0.70710678118654752f));
}

__device__ __forceinline__ void gload_lds16(const void* g, void* l) {
    __builtin_amdgcn_global_load_lds(
        (const __attribute__((address_space(1))) void*)g,
        (__attribute__((address_space(3))) void*)l, 16, 0, 0);
}

// ---------------------------------------------------------------------------
// Embedding: h (f32) = inp_emb[x] + pos_emb. 4 elems/thread, float4 I/O.
// ---------------------------------------------------------------------------
__global__ __launch_bounds__(256) void embed_kernel(
    const int* __restrict__ x, const float* __restrict__ inp_emb,
    const float* __restrict__ pos_emb, float* __restrict__ h)
{
    const int idx = (blockIdx.x * 256 + threadIdx.x) * 4;
    const int bt  = idx >> 10;
    const int d   = idx & 1023;
    const int t   = bt & (SEQ_T - 1);
    const int tok = x[bt];
    const float4 a = *(const float4*)(inp_emb + (size_t)tok * D_MODEL + d);
    const float4 b = *(const float4*)(pos_emb + (size_t)t * D_MODEL + d);
    float4 o;
    o.x = a.x + b.x;
    o.y = a.y + b.y;
    o.z = a.z + b.z;
    o.w = a.w + b.w;
    *(float4*)(h + idx) = o;
}

// ---------------------------------------------------------------------------
// LayerNorm body (D=1024), f32 in, bf16 out. One 256-thr block per row.
// ---------------------------------------------------------------------------
__device__ __forceinline__ void ln_row(
    const float* __restrict__ x, const float* __restrict__ sc,
    const float* __restrict__ bi, __bf16* __restrict__ o, int row, int tid)
{
    const int c = tid * 4;
    const float4 v = *(const float4*)(x + (size_t)row * D_MODEL + c);
    float sum = v.x + v.y + v.z + v.w;
    float sq  = v.x * v.x + v.y * v.y + v.z * v.z + v.w * v.w;
    #pragma unroll
    for (int off = 32; off > 0; off >>= 1) {
        sum += __shfl_xor(sum, off);
        sq  += __shfl_xor(sq, off);
    }
    __shared__ float ssum[4], ssq[4];
    const int wave = tid >> 6, lane = tid & 63;
    if (lane == 0) { ssum[wave] = sum; ssq[wave] = sq; }
    __syncthreads();
    sum = ssum[0] + ssum[1] + ssum[2] + ssum[3];
    sq  = ssq[0]  + ssq[1]  + ssq[2]  + ssq[3];
    const float mu  = sum * (1.0f / D_MODEL);
    const float var = sq * (1.0f / D_MODEL) - mu * mu;
    const float rs  = rsqrtf(var + 1e-5f);
    const float4 s4 = *(const float4*)(sc + c);
    const float4 b4 = *(const float4*)(bi + c);
    bf16x4v ov;
    ov[0] = (__bf16)((v.x - mu) * rs * s4.x + b4.x);
    ov[1] = (__bf16)((v.y - mu) * rs * s4.y + b4.y);
    ov[2] = (__bf16)((v.z - mu) * rs * s4.z + b4.z);
    ov[3] = (__bf16)((v.w - mu) * rs * s4.w + b4.w);
    *(bf16x4v*)(o + (size_t)row * D_MODEL + c) = ov;
}

__global__ __launch_bounds__(256) void layernorm_kernel(
    const float* __restrict__ x, const float* __restrict__ sc,
    const float* __restrict__ bi, __bf16* __restrict__ o)
{
    ln_row(x, sc, bi, o, blockIdx.x, threadIdx.x);
}

// ---------------------------------------------------------------------------
// w_out transpose: f32 [1024][32000] -> bf16 [32000][1024]. 32x64 tiles,
// bf16x8 writes. Launched RIGHT BEFORE the logits GEMM so woutT is
// L3-resident when the GEMM reads it (r8 vs r11: 185 vs 241 us on logits).
// ---------------------------------------------------------------------------
__global__ __launch_bounds__(256) void wout_tr_kernel(
    const float* __restrict__ in, __bf16* __restrict__ out)
{
    __shared__ __bf16 tile[32][72];
    const int tid = threadIdx.x;
    const int t   = blockIdx.x;
    const int kb0 = (t & 31) * 32;
    const int nb0 = (t >> 5) * 64;
    {
        const int rr = tid >> 3, c8 = (tid & 7) * 8;
        const float* p = in + (size_t)(kb0 + rr) * VOCAB + nb0 + c8;
        const float4 v0 = *(const float4*)p;
        const float4 v1 = *(const float4*)(p + 4);
        tile[rr][c8 + 0] = (__bf16)v0.x;
        tile[rr][c8 + 1] = (__bf16)v0.y;
        tile[rr][c8 + 2] = (__bf16)v0.z;
        tile[rr][c8 + 3] = (__bf16)v0.w;
        tile[rr][c8 + 4] = (__bf16)v1.x;
        tile[rr][c8 + 5] = (__bf16)v1.y;
        tile[rr][c8 + 6] = (__bf16)v1.z;
        tile[rr][c8 + 7] = (__bf16)v1.w;
    }
    __syncthreads();
    {
        const int cc = tid >> 2, k8 = (tid & 3) * 8;
        bf16x8 ov;
        #pragma unroll
        for (int e = 0; e < 8; ++e) ov[e] = tile[k8 + e][cc];
        *(bf16x8*)(out + (size_t)(nb0 + cc) * D_MODEL + kb0 + k8) = ov;
    }
}

// ---------------------------------------------------------------------------
// Merged per-layer dispatch: LN1 (blocks 0..2047) + 6 weight transposes
// (f32 [K][N] -> bf16 [N][K], 32x64 tiles, bf16x8 writes) + qkv bias concat.
// ---------------------------------------------------------------------------
__global__ __launch_bounds__(256) void prep_ln_kernel(
    const float* __restrict__ h, const float* __restrict__ ln_s,
    const float* __restrict__ ln_b, __bf16* __restrict__ xn,
    const float* __restrict__ wq, const float* __restrict__ wk,
    const float* __restrict__ wv, const float* __restrict__ wo,
    const float* __restrict__ w1, const float* __restrict__ w2,
    const float* __restrict__ bq, const float* __restrict__ bk,
    const float* __restrict__ bv,
    __bf16* __restrict__ wqkvT, __bf16* __restrict__ woT,
    __bf16* __restrict__ w1T, __bf16* __restrict__ w2T,
    float* __restrict__ bqkv)
{
    const int tid = threadIdx.x;
    const int b   = blockIdx.x;

    if (b < 2048) {                       // LN1
        ln_row(h, ln_s, ln_b, xn, b, tid);
        return;
    }
    const int pb = b - 2048;
    if (pb >= 6144) {                     // bias concat (12 blocks)
        const int j = (pb - 6144) * 256 + tid;
        bqkv[j] = (j < 1024) ? bq[j] : (j < 2048 ? bk[j - 1024] : bv[j - 2048]);
        return;
    }

    // 32(K) x 64(N) transpose tile
    __shared__ __bf16 tile[32][72];
    const float* in;
    __bf16* out;
    int K, N, kb0, nb0;
    if (pb < 2048) {                      // wq/wk/wv/wo: 512 tiles each
        const int w = pb >> 9, t = pb & 511;
        K = 1024; N = 1024; kb0 = (t >> 4) * 32; nb0 = (t & 15) * 64;
        in  = (w == 0) ? wq : (w == 1) ? wk : (w == 2) ? wv : wo;
        out = (w == 3) ? woT : wqkvT + (size_t)w * 1024 * 1024;
    } else if (pb < 4096) {               // w1: K=1024, N=4096
        const int t = pb - 2048;
        K = 1024; N = 4096; kb0 = (t >> 6) * 32; nb0 = (t & 63) * 64;
        in = w1; out = w1T;
    } else {                              // w2: K=4096, N=1024
        const int t = pb - 4096;
        K = 4096; N = 1024; kb0 = (t >> 4) * 32; nb0 = (t & 15) * 64;
        in = w2; out = w2T;
    }

    {   // read: 32 rows x 64 cols, 8 f32 per thread
        const int rr = tid >> 3, c8 = (tid & 7) * 8;
        const float* p = in + (size_t)(kb0 + rr) * N + nb0 + c8;
        const float4 v0 = *(const float4*)p;
        const float4 v1 = *(const float4*)(p + 4);
        tile[rr][c8 + 0] = (__bf16)v0.x;
        tile[rr][c8 + 1] = (__bf16)v0.y;
        tile[rr][c8 + 2] = (__bf16)v0.z;
        tile[rr][c8 + 3] = (__bf16)v0.w;
        tile[rr][c8 + 4] = (__bf16)v1.x;
        tile[rr][c8 + 5] = (__bf16)v1.y;
        tile[rr][c8 + 6] = (__bf16)v1.z;
        tile[rr][c8 + 7] = (__bf16)v1.w;
    }
    __syncthreads();
    {   // write: 64 cols x 32 k, bf16x8 (16B) per thread
        const int cc = tid >> 2, k8 = (tid & 3) * 8;
        bf16x8 ov;
        #pragma unroll
        for (int e = 0; e < 8; ++e) ov[e] = tile[k8 + e][cc];
        *(bf16x8*)(out + (size_t)(nb0 + cc) * K + kb0 + k8) = ov;
    }
}

// ---------------------------------------------------------------------------
// GEMM: C[M,N] = epi(A[M,K] @ Bt[N,K]^T + bias). bf16 in, f32 acc.
// Single-buffered m97 structure: 128 x BN_T tile, BK=64, global_load_lds
// staging, XOR-granule swizzle both sides, M-fast grid + XCD chunking.
// BN_T=32 used for N=1024 GEMMs (wo, w2): 512 blocks = 2/CU so a
// co-resident block fills the per-K-step barrier drain (1/CU has none).
// NT: direct nontemporal C stores (streaming output).
// ---------------------------------------------------------------------------
template <int BN_T, int EPI, typename OutT, bool NT = false>
__global__ __launch_bounds__(256) void gemm_bt(
    const __bf16* __restrict__ A, const __bf16* __restrict__ Bt,
    const float* __restrict__ bias, const float* __restrict__ res,
    OutT* __restrict__ C, int M, int N, int K)
{
    constexpr int NF  = BN_T / 32;      // N fragments per wave (>=1)
    constexpr int NCB = BN_T / 8;       // B 1KB-chunks
    __shared__ __bf16 As[128 * 64];
    __shared__ __bf16 Bs[BN_T * 64];

    const int tid  = threadIdx.x;
    const int wave = tid >> 6;
    const int lane = tid & 63;
    const int r    = lane & 15;
    const int kb   = lane >> 4;
    const int wm   = wave >> 1;
    const int wn   = wave & 1;

    const int ntm = gridDim.x;
    const int nwg = ntm * gridDim.y;
    int bid = blockIdx.y * ntm + blockIdx.x;
    if ((nwg & 7) == 0) bid = (bid & 7) * (nwg >> 3) + (bid >> 3);
    const int bm = (bid % ntm) * 128;
    const int bn = (bid / ntm) * BN_T;

    const int srow = lane >> 3;
    const int sg   = lane & 7;

    f32x4 acc[4][NF] = {};

    for (int k0 = 0; k0 < K; k0 += 64) {
        #pragma unroll
        for (int i = 0; i < 4; ++i) {
            const int c    = i * 4 + wave;
            const int row  = c * 8 + srow;
            const int scol = (sg ^ (row & 7)) * 8;
            gload_lds16(A + (size_t)(bm + row) * K + k0 + scol, &As[c * 512]);
        }
        #pragma unroll
        for (int i = 0; i < (NCB + 3) / 4; ++i) {
            const int c = i * 4 + wave;
            if (c < NCB) {
                const int row  = c * 8 + srow;
                const int scol = (sg ^ (row & 7)) * 8;
                gload_lds16(Bt + (size_t)(bn + row) * K + k0 + scol, &Bs[c * 512]);
            }
        }
        __syncthreads();

        #pragma unroll
        for (int s = 0; s < 2; ++s) {
            bf16x8 af[4];
            #pragma unroll
            for (int m = 0; m < 4; ++m) {
                const int row = wm * 64 + m * 16 + r;
                const int g   = (s * 4 + kb) ^ (row & 7);
                af[m] = *(const bf16x8*)&As[row * 64 + g * 8];
            }
            #pragma unroll
            for (int n = 0; n < NF; ++n) {
                const int row = wn * (NF * 16) + n * 16 + r;
                const int g   = (s * 4 + kb) ^ (row & 7);
                const bf16x8 bfr = *(const bf16x8*)&Bs[row * 64 + g * 8];
                #pragma unroll
                for (int m = 0; m < 4; ++m)
                    acc[m][n] = __builtin_amdgcn_mfma_f32_16x16x32_bf16(af[m], bfr, acc[m][n], 0, 0, 0);
            }
        }
        __syncthreads();
    }

    #pragma unroll
    for (int m = 0; m < 4; ++m) {
        const int row = bm + wm * 64 + m * 16 + kb * 4;
        #pragma unroll
        for (int n = 0; n < NF; ++n) {
            const int col = bn + wn * (NF * 16) + n * 16 + r;
            const float bv = bias ? bias[col] : 0.0f;
            #pragma unroll
            for (int rg = 0; rg < 4; ++rg) {
                float v = acc[m][n][rg] + bv;
                if constexpr (EPI == 1) v += res[(size_t)(row + rg) * N + col];
                if constexpr (EPI == 2) v = gelu_f(v);
                if constexpr (NT) {
                    __builtin_nontemporal_store((OutT)v, &C[(size_t)(row + rg) * N + col]);
                } else {
                    C[(size_t)(row + rg) * N + col] = (OutT)v;
                }
            }
        }
    }
}

// ---------------------------------------------------------------------------
// Balanced MFMA flash attention (causal), bf16 packed qkv (row stride 3072).
// One block = (b, h, query-tile PAIR {i, 15-i}), 4 waves x 16 q per tile.
// Diagonal-only masking + defer-max (THR=8) + T14 async-STAGE split.
// ---------------------------------------------------------------------------
struct AttnState {
    float m[4];
    float l[4];
    f32x4 yacc[4];
};

template <bool MASK>
__device__ __forceinline__ void attn_tile_step(
    AttnState& st, const bf16x8 (&qf)[2], int q0, int kt,
    int wave, int r, int kb,
    const __bf16 (*K_lds)[72], const __bf16 (*V_lds)[72],
    __bf16 (*P_row)[72])
{
    f32x4 sacc[4] = {};
    #pragma unroll
    for (int kc = 0; kc < 2; ++kc) {
        #pragma unroll
        for (int g = 0; g < 4; ++g) {
            const bf16x8 kf = *(const bf16x8*)&K_lds[g * 16 + r][kc * 32 + kb * 8];
            sacc[g] = __builtin_amdgcn_mfma_f32_16x16x32_bf16(qf[kc], kf, sacc[g], 0, 0, 0);
        }
    }

    float s[4][4], p[4][4];
    #pragma unroll
    for (int g = 0; g < 4; ++g) {
        #pragma unroll
        for (int rg = 0; rg < 4; ++rg) {
            if constexpr (MASK) {
                const int key = kt * 64 + g * 16 + r;
                const int qq  = q0 + wave * 16 + kb * 4 + rg;
                s[g][rg] = (key <= qq) ? sacc[g][rg] * 0.125f : -INFINITY;
            } else {
                s[g][rg] = sacc[g][rg] * 0.125f;
            }
        }
    }

    float mt[4];
    #pragma unroll
    for (int rg = 0; rg < 4; ++rg)
        mt[rg] = fmaxf(fmaxf(s[0][rg], s[1][rg]), fmaxf(s[2][rg], s[3][rg]));
    #pragma unroll
    for (int off = 1; off < 16; off <<= 1) {
        #pragma unroll
        for (int rg = 0; rg < 4; ++rg) mt[rg] = fmaxf(mt[rg], __shfl_xor(mt[rg], off));
    }

    bool grow = false;
    #pragma unroll
    for (int rg = 0; rg < 4; ++rg) grow |= (mt[rg] > st.m[rg] + 8.0f);
    if (__any(grow)) {
        #pragma unroll
        for (int rg = 0; rg < 4; ++rg) {
            const float mn   = fmaxf(st.m[rg], mt[rg]);
            const float corr = __expf(st.m[rg] - mn);
            st.l[rg] *= corr;
            st.m[rg]  = mn;
            #pragma unroll
            for (int n = 0; n < 4; ++n) st.yacc[n][rg] *= corr;
        }
    }

    float psum[4];
    #pragma unroll
    for (int rg = 0; rg < 4; ++rg) {
        psum[rg] = 0.0f;
        #pragma unroll
        for (int g = 0; g < 4; ++g) {
            p[g][rg] = __expf(s[g][rg] - st.m[rg]);
            psum[rg] += p[g][rg];
        }
    }
    #pragma unroll
    for (int off = 1; off < 16; off <<= 1) {
        #pragma unroll
        for (int rg = 0; rg < 4; ++rg) psum[rg] += __shfl_xor(psum[rg], off);
    }
    #pragma unroll
    for (int rg = 0; rg < 4; ++rg) st.l[rg] += psum[rg];

    #pragma unroll
    for (int g = 0; g < 4; ++g) {
        #pragma unroll
        for (int rg = 0; rg < 4; ++rg)
            P_row[kb * 4 + rg][g * 16 + r] = (__bf16)p[g][rg];
    }
    const bf16x8 pa0 = *(const bf16x8*)&P_row[r][kb * 8];
    const bf16x8 pa1 = *(const bf16x8*)&P_row[r][32 + kb * 8];

    #pragma unroll
    for (int n = 0; n < 4; ++n) {
        const int vrow = n * 16 + r;
        const int swz  = (vrow >> 3) & 7;
        const bf16x8 vf0 = *(const bf16x8*)&V_lds[vrow][(kb ^ swz) * 8];
        st.yacc[n] = __builtin_amdgcn_mfma_f32_16x16x32_bf16(pa0, vf0, st.yacc[n], 0, 0, 0);
    }
    #pragma unroll
    for (int n = 0; n < 4; ++n) {
        const int vrow = n * 16 + r;
        const int swz  = (vrow >> 3) & 7;
        const bf16x8 vf1 = *(const bf16x8*)&V_lds[vrow][((kb + 4) ^ swz) * 8];
        st.yacc[n] = __builtin_amdgcn_mfma_f32_16x16x32_bf16(pa1, vf1, st.yacc[n], 0, 0, 0);
    }
}

__global__ __launch_bounds__(256) void attn_mfma_kernel(
    const __bf16* __restrict__ qkv, __bf16* __restrict__ y)
{
    constexpr int QS = 3 * D_MODEL;
    __shared__ __align__(16) __bf16 K_lds[64][72];
    __shared__ __align__(16) __bf16 V_lds[64][72];
    __shared__ __align__(16) __bf16 P_lds[4][16][72];

    const int tid  = threadIdx.x;
    const int wave = tid >> 6;
    const int lane = tid & 63;
    const int r    = lane & 15;
    const int kb   = lane >> 4;

    const int ip  = blockIdx.x;           // 0..7
    const int q0A = ip * 64;
    const int q0B = (15 - ip) * 64;
    const int b   = blockIdx.y >> 4;
    const int h   = blockIdx.y & 15;

    const __bf16* qp = qkv + (size_t)b * SEQ_T * QS + h * DKH;
    const __bf16* kp = qp + D_MODEL;
    const __bf16* vp = qp + 2 * D_MODEL;
    __bf16* yp = y + (size_t)b * SEQ_T * D_MODEL + h * DKH;

    bf16x8 qfA[2], qfB[2];
    {
        const int qrA = q0A + wave * 16 + r;
        const int qrB = q0B + wave * 16 + r;
        #pragma unroll
        for (int kc = 0; kc < 2; ++kc) {
            qfA[kc] = *(const bf16x8*)(qp + (size_t)qrA * QS + kc * 32 + kb * 8);
            qfB[kc] = *(const bf16x8*)(qp + (size_t)qrB * QS + kc * 32 + kb * 8);
        }
    }

    AttnState stA, stB;
    #pragma unroll
    for (int rg = 0; rg < 4; ++rg) {
        stA.m[rg] = -INFINITY; stA.l[rg] = 0.0f;
        stB.m[rg] = -INFINITY; stB.l[rg] = 0.0f;
    }
    #pragma unroll
    for (int n = 0; n < 4; ++n) { stA.yacc[n] = {}; stB.yacc[n] = {}; }

    const int skey = tid >> 2;          // 0..63
    const int sg16 = (tid & 3) * 16;    // 0,16,32,48
    const int swz0 = ((sg16 >> 3) & 7) * 8;
    const int swz1 = (((sg16 + 8) >> 3) & 7) * 8;

    const int ntiles = 16 - ip;

    // prologue: stage tile 0 into registers
    bf16x8 kr0, kr1, vr0, vr1;
    {
        const size_t go = (size_t)skey * QS;
        kr0 = *(const bf16x8*)(kp + go + sg16);
        kr1 = *(const bf16x8*)(kp + go + sg16 + 8);
        vr0 = *(const bf16x8*)(vp + go + sg16);
        vr1 = *(const bf16x8*)(vp + go + sg16 + 8);
    }

    for (int kt = 0; kt < ntiles; ++kt) {
        // write staged registers to LDS
        *(bf16x8*)&K_lds[skey][sg16]     = kr0;
        *(bf16x8*)&K_lds[skey][sg16 + 8] = kr1;
        #pragma unroll
        for (int j = 0; j < 8; ++j)
            V_lds[sg16 + j][skey ^ swz0] = vr0[j];
        #pragma unroll
        for (int j = 0; j < 8; ++j)
            V_lds[sg16 + 8 + j][skey ^ swz1] = vr1[j];
        __syncthreads();

        // issue next tile's loads early (latency hides under compute)
        if (kt + 1 < ntiles) {
            const size_t go = (size_t)((kt + 1) * 64 + skey) * QS;
            kr0 = *(const bf16x8*)(kp + go + sg16);
            kr1 = *(const bf16x8*)(kp + go + sg16 + 8);
            vr0 = *(const bf16x8*)(vp + go + sg16);
            vr1 = *(const bf16x8*)(vp + go + sg16 + 8);
        }

        if (kt == ntiles - 1)
            attn_tile_step<true >(stB, qfB, q0B, kt, wave, r, kb, K_lds, V_lds, P_lds[wave]);
        else
            attn_tile_step<false>(stB, qfB, q0B, kt, wave, r, kb, K_lds, V_lds, P_lds[wave]);
        if (kt <= ip) {
            if (kt == ip)
                attn_tile_step<true >(stA, qfA, q0A, kt, wave, r, kb, K_lds, V_lds, P_lds[wave]);
            else
                attn_tile_step<false>(stA, qfA, q0A, kt, wave, r, kb, K_lds, V_lds, P_lds[wave]);
        }
        __syncthreads();
    }

    float invA[4], invB[4];
    #pragma unroll
    for (int rg = 0; rg < 4; ++rg) {
        invA[rg] = 1.0f / stA.l[rg];
        invB[rg] = 1.0f / stB.l[rg];
    }
    #pragma unroll
    for (int n = 0; n < 4; ++n) {
        #pragma unroll
        for (int rg = 0; rg < 4; ++rg) {
            const int rowA = q0A + wave * 16 + kb * 4 + rg;
            const int rowB = q0B + wave * 16 + kb * 4 + rg;
            yp[(size_t)rowA * D_MODEL + n * 16 + r] = (__bf16)(stA.yacc[n][rg] * invA[rg]);
            yp[(size_t)rowB * D_MODEL + n * 16 + r] = (__bf16)(stB.yacc[n][rg] * invB[rg]);
        }
    }
}

// ---------------------------------------------------------------------------
extern "C" void kernel_launch(void* const* d_in, const int* in_sizes, int n_in,
                              void* d_out, int out_size, void* d_ws, size_t ws_size,
                              hipStream_t stream)
{
    const int*   x       = (const int*)  d_in[0];
    const float* inp_emb = (const float*)d_in[1];
    const float* pos_emb = (const float*)d_in[2];
    const float* wq = (const float*)d_in[3];
    const float* bq = (const float*)d_in[4];
    const float* wk = (const float*)d_in[5];
    const float* bk = (const float*)d_in[6];
    const float* wv = (const float*)d_in[7];
    const float* bv = (const float*)d_in[8];
    const float* wo = (const float*)d_in[9];
    const float* bo = (const float*)d_in[10];
    const float* w1 = (const float*)d_in[11];
    const float* b1 = (const float*)d_in[12];
    const float* w2 = (const float*)d_in[13];
    const float* b2 = (const float*)d_in[14];
    const float* ln1_s = (const float*)d_in[15];
    const float* ln1_b = (const float*)d_in[16];
    const float* ln2_s = (const float*)d_in[17];
    const float* ln2_b = (const float*)d_in[18];
    const float* lno_s = (const float*)d_in[19];
    const float* lno_b = (const float*)d_in[20];
    const float* w_out = (const float*)d_in[21];

    const int M = BATCH * SEQ_T;                 // 2048
    const size_t MB = 1u << 20;

    char* w = (char*)d_ws;
    float*  h     = (float*) (w + 0);            // 8MB
    __bf16* xn    = (__bf16*)(w + 8  * MB);      // 4MB
    __bf16* yb    = (__bf16*)(w + 12 * MB);      // 4MB
    __bf16* sh    = (__bf16*)(w + 16 * MB);      // qkv/mid 16MB
    __bf16* wqkvT = (__bf16*)(w + 32 * MB);      // 6MB
    __bf16* woT   = (__bf16*)(w + 38 * MB);      // 2MB
    __bf16* w1T   = (__bf16*)(w + 40 * MB);      // 8MB
    __bf16* w2T   = (__bf16*)(w + 48 * MB);      // 8MB
    float*  bqkv  = (float*) (w + 56 * MB);      // 12KB
    __bf16* woutT = (__bf16*)(w + 57 * MB);      // 62.5MB

    embed_kernel<<<dim3(M * D_MODEL / 1024), 256, 0, stream>>>(x, inp_emb, pos_emb, h);

    for (int i = 0; i < NLAYERS; ++i) {
        const size_t wOff  = (size_t)i * D_MODEL * D_MODEL;
        const size_t w1Off = (size_t)i * D_MODEL * DFF_;

        // merged: LN1 + weight prep
        prep_ln_kernel<<<dim3(2048 + 6156), 256, 0, stream>>>(
            h, ln1_s + i * D_MODEL, ln1_b + i * D_MODEL, xn,
            wq + wOff, wk + wOff, wv + wOff, wo + wOff, w1 + w1Off, w2 + w1Off,
            bq + i * D_MODEL, bk + i * D_MODEL, bv + i * D_MODEL,
            wqkvT, woT, w1T, w2T, bqkv);

        gemm_bt<64, 0, __bf16><<<dim3(M / 128, 3 * D_MODEL / 64), 256, 0, stream>>>(
            xn, wqkvT, bqkv, nullptr, sh, M, 3 * D_MODEL, D_MODEL);
        attn_mfma_kernel<<<dim3(8, BATCH * N_HEADS), 256, 0, stream>>>(sh, yb);
        // wo: BN_T=32 -> 512 blocks = 2/CU (was 256 = 1/CU)
        gemm_bt<32, 1, float><<<dim3(M / 128, D_MODEL / 32), 256, 0, stream>>>(
            yb, woT, bo + i * D_MODEL, h, h, M, D_MODEL, D_MODEL);
        layernorm_kernel<<<dim3(M), 256, 0, stream>>>(h, ln2_s + i * D_MODEL, ln2_b + i * D_MODEL, xn);
        gemm_bt<128, 2, __bf16><<<dim3(M / 128, DFF_ / 128), 256, 0, stream>>>(
            xn, w1T, b1 + i * DFF_, nullptr, sh, M, DFF_, D_MODEL);
        // w2: BN_T=32 -> 512 blocks = 2/CU (was 256 = 1/CU)
        gemm_bt<32, 1, float><<<dim3(M / 128, D_MODEL / 32), 256, 0, stream>>>(
            sh, w2T, b2 + i * D_MODEL, h, h, M, D_MODEL, DFF_);
    }

    // w_out transpose RIGHT BEFORE logits: woutT stays L3-resident for the GEMM
    wout_tr_kernel<<<dim3(16000), 256, 0, stream>>>(w_out, woutT);
    layernorm_kernel<<<dim3(M), 256, 0, stream>>>(h, lno_s, lno_b, xn);
    gemm_bt<128, 0, float, true><<<dim3(M / 128, VOCAB / 128), 256, 0, stream>>>(
        xn, woutT, nullptr, nullptr, (float*)d_out, M, VOCAB, D_MODEL);
}